// Round 16
// baseline (1478.714 us; speedup 1.0000x reference)
//
#include <hip/hip_runtime.h>
#include <stdint.h>

// Problem constants
#define T_TOKENS 16384
#define H_DIM 1024
#define E_NUM 8
#define DFF_DIM 4096

// GEMM tiling
#define BMT 128
#define BNT 128
#define BKT 64
#define NCHUNK 4
#define MT1_PER_CHUNK 68                 // fc1 128-row tiles per chunk
#define MT2_PER_CHUNK 34                 // fc2 256-row tiles per chunk
#define CHUNK_ROWS 8704                  // 34 x 256 = 68 x 128
#define PAD_MAX (NCHUNK * CHUNK_ROWS)    // 34816 (>= 32768 + 8*255 max padded)

// Workspace layout (bytes) — total 273,031,424 <= 273,162,496 (proven round 0)
#define WS_COUNTS     0
#define WS_CURSOR     32
#define WS_OFFS       64
#define WS_SLOT_TOK   256                // 34816 x 4 = 139,264
#define WS_EIDX       139520             // 131,072
#define WS_EW         270592             // 131,072
#define WS_WC1        401664             // 67,108,864
#define WS_WC2        67510528           // 67,108,864
#define WS_XB         134619392          // 33,554,432
#define WS_HDN        168173824          // 8704 x 4096 x 2 = 71,303,168
#define WS_OUTK1      239476992          // 33,554,432
#define WS_REQUIRED   273031424UL
#define WS_SMALL_ZERO 139520             // counts/cursor/offs/slot_token

typedef __attribute__((ext_vector_type(8))) short short8;
typedef __attribute__((ext_vector_type(4))) float f32x4;

__device__ __forceinline__ unsigned short f2bf(float f) {
  union { float f; unsigned int u; } v; v.f = f;
  unsigned int r = v.u + 0x7FFFu + ((v.u >> 16) & 1u);  // round-nearest-even
  return (unsigned short)(r >> 16);
}

__device__ __forceinline__ float bf2f(unsigned short b) {
  union { unsigned int u; float f; } v; v.u = ((unsigned int)b) << 16;
  return v.f;
}

__device__ __forceinline__ void load_lds16(const void* g, void* l) {
  __builtin_amdgcn_global_load_lds(
      (const __attribute__((address_space(1))) void*)g,
      (__attribute__((address_space(3))) void*)l, 16, 0, 0);
}

// ---------------------------------------------------------------------------
// Weight fp32 -> bf16 conversion (grid-stride; round-15 validated).
// ---------------------------------------------------------------------------
#define CONV_BLOCKS 2048
__global__ __launch_bounds__(256) void convert_weights(
    const float* __restrict__ w1, const float* __restrict__ w2,
    unsigned short* __restrict__ wc1, unsigned short* __restrict__ wc2) {
  const int total4 = (E_NUM * DFF_DIM * H_DIM) / 4;  // 8388608
  const int step = CONV_BLOCKS * 256;
  for (int i = blockIdx.x * 256 + threadIdx.x; i < total4; i += step) {
    float4 a = ((const float4*)w1)[i];
    float4 b = ((const float4*)w2)[i];
    ushort4 ua, ub;
    ua.x = f2bf(a.x); ua.y = f2bf(a.y); ua.z = f2bf(a.z); ua.w = f2bf(a.w);
    ub.x = f2bf(b.x); ub.y = f2bf(b.y); ub.z = f2bf(b.z); ub.w = f2bf(b.w);
    ((ushort4*)wc1)[i] = ua;
    ((ushort4*)wc2)[i] = ub;
  }
}

// ---------------------------------------------------------------------------
// Router: no global atomics (round-2 lesson). Emits x as bf16 (xb).
// ---------------------------------------------------------------------------
__global__ __launch_bounds__(256) void router_kernel(
    const float* __restrict__ x, const float* __restrict__ rw,
    const float* __restrict__ rb, unsigned short* __restrict__ xb,
    int* __restrict__ eidx, float* __restrict__ ew) {
  __shared__ float4 rws[E_NUM * 256];
  const int tid = threadIdx.x;
#pragma unroll
  for (int k = 0; k < 8; ++k) rws[k * 256 + tid] = ((const float4*)rw)[k * 256 + tid];
  __syncthreads();

  const int wave = tid >> 6;
  const int lane = tid & 63;
#pragma unroll
  for (int i = 0; i < 4; ++i) {
    const int t = blockIdx.x * 16 + wave * 4 + i;
    const float4* xrow = (const float4*)(x + (size_t)t * H_DIM);
    float4 xv[4];
#pragma unroll
    for (int j = 0; j < 4; ++j) xv[j] = xrow[j * 64 + lane];

    ushort4* xbrow = (ushort4*)(xb + (size_t)t * H_DIM);
#pragma unroll
    for (int j = 0; j < 4; ++j) {
      ushort4 o;
      o.x = f2bf(xv[j].x); o.y = f2bf(xv[j].y);
      o.z = f2bf(xv[j].z); o.w = f2bf(xv[j].w);
      xbrow[j * 64 + lane] = o;
    }

    float s[E_NUM];
#pragma unroll
    for (int e = 0; e < E_NUM; ++e) {
      float a = 0.f;
#pragma unroll
      for (int j = 0; j < 4; ++j) {
        float4 wv = rws[e * 256 + j * 64 + lane];
        a += xv[j].x * wv.x + xv[j].y * wv.y + xv[j].z * wv.z + xv[j].w * wv.w;
      }
      s[e] = a;
    }
#pragma unroll
    for (int off = 32; off; off >>= 1) {
#pragma unroll
      for (int e = 0; e < E_NUM; ++e) s[e] += __shfl_xor(s[e], off);
    }
    if (lane == 0) {
      float lg[E_NUM];
#pragma unroll
      for (int e = 0; e < E_NUM; ++e) lg[e] = s[e] + rb[e];
      int i0 = 0; float m0 = lg[0];
#pragma unroll
      for (int e = 1; e < E_NUM; ++e)
        if (lg[e] > m0) { m0 = lg[e]; i0 = e; }
      int i1 = -1; float m1 = -3.4e38f;
#pragma unroll
      for (int e = 0; e < E_NUM; ++e)
        if (e != i0 && lg[e] > m1) { m1 = lg[e]; i1 = e; }
      float e1 = expf(m1 - m0);
      float denom = 1.f + e1;
      ((int2*)eidx)[t] = make_int2(i0, i1);
      ((float2*)ew)[t] = make_float2(1.f / denom, e1 / denom);
    }
  }
}

// ---------------------------------------------------------------------------
// count_kernel: register histogram, LDS atomics only. Offs padded to 256
// (fc2's 256-row tiles must not straddle experts).
// ---------------------------------------------------------------------------
__global__ __launch_bounds__(1024) void count_kernel(const int* __restrict__ eidx,
                                                     int* __restrict__ counts,
                                                     int* __restrict__ offs,
                                                     int* __restrict__ cursor) {
  __shared__ int hist[E_NUM];
  const int tid = threadIdx.x;
  const int lane = tid & 63;
  if (tid < E_NUM) hist[tid] = 0;
  __syncthreads();
  int c[E_NUM];
#pragma unroll
  for (int e = 0; e < E_NUM; ++e) c[e] = 0;
  const int4* p = (const int4*)eidx;
#pragma unroll
  for (int i = 0; i < 8; ++i) {
    int4 v = p[i * 1024 + tid];
#pragma unroll
    for (int e = 0; e < E_NUM; ++e)
      c[e] += (v.x == e) + (v.y == e) + (v.z == e) + (v.w == e);
  }
#pragma unroll
  for (int off = 32; off; off >>= 1) {
#pragma unroll
    for (int e = 0; e < E_NUM; ++e) c[e] += __shfl_xor(c[e], off);
  }
  if (lane == 0) {
#pragma unroll
    for (int e = 0; e < E_NUM; ++e) atomicAdd(&hist[e], c[e]);
  }
  __syncthreads();
  if (tid == 0) {
    int acc = 0;
    offs[0] = 0;
#pragma unroll
    for (int e = 0; e < E_NUM; ++e) {
      counts[e] = hist[e];
      cursor[e] = 0;
      acc += ((hist[e] + 255) / 256) * 256;   // 256-aligned for fc2 tiles
      offs[e + 1] = acc;
    }
  }
}

// ---------------------------------------------------------------------------
// Scatter: ballot-rank compaction (128 global atomics total). slot_token
// carries the k-flag in bit 31; weights read from ew[2*tok+k] downstream
// (slot_w array dropped to fit workspace).
// ---------------------------------------------------------------------------
__global__ __launch_bounds__(1024) void scatter_kernel(
    const int* __restrict__ eidx, const int* __restrict__ offs,
    int* __restrict__ cursor, int* __restrict__ slot_token) {
  __shared__ int wcnt[16][E_NUM];
  __shared__ int wpre[16][E_NUM];
  __shared__ int bbase[E_NUM];
  __shared__ int soffs[E_NUM];
  const int tid = threadIdx.x, w = tid >> 6, lane = tid & 63;
  const int t = blockIdx.x * 1024 + tid;
  const int2 epair = ((const int2*)eidx)[t];
  const int e0 = epair.x, e1 = epair.y;
  const unsigned long long lt = (1ULL << lane) - 1ULL;
  if (tid < E_NUM) soffs[tid] = offs[tid];
  int r0 = 0, r1 = 0;
#pragma unroll
  for (int e = 0; e < E_NUM; ++e) {
    unsigned long long m0 = __ballot(e0 == e);
    unsigned long long m1 = __ballot(e1 == e);
    int c0 = __popcll(m0);
    if (e0 == e) r0 = __popcll(m0 & lt);
    if (e1 == e) r1 = c0 + __popcll(m1 & lt);
    if (lane == 0) wcnt[w][e] = c0 + __popcll(m1);
  }
  __syncthreads();
  if (tid < E_NUM) {
    int run = 0;
#pragma unroll
    for (int w2 = 0; w2 < 16; ++w2) {
      wpre[w2][tid] = run;
      run += wcnt[w2][tid];
    }
    bbase[tid] = atomicAdd(&cursor[tid], run);
  }
  __syncthreads();
  const int s0 = soffs[e0] + bbase[e0] + wpre[w][e0] + r0;
  const int s1 = soffs[e1] + bbase[e1] + wpre[w][e1] + r1;
  slot_token[s0] = t;                       // k=0
  slot_token[s1] = t | (int)0x80000000;     // k=1
}

// ---------------------------------------------------------------------------
// fc1 GEMM core (BK=64, 1-phase, 256 thr — proven 886 TF at high churn).
// ---------------------------------------------------------------------------
template <int KTOT>
__device__ __forceinline__ void gemm_core(const unsigned short* const* aptr,
                                          const unsigned short* const* bptr,
                                          unsigned short* lA, unsigned short* lB,
                                          f32x4 acc[4][4]) {
  const int tid = threadIdx.x;
  const int w = tid >> 6, lane = tid & 63;
  const int wm = w >> 1, wn = w & 1;
  const int rrow = lane & 15;
  const int rq = lane >> 4;

  for (int ks = 0; ks < KTOT / BKT; ++ks) {
    const int k0 = ks * BKT;
#pragma unroll
    for (int i = 0; i < 4; ++i) {
      load_lds16(aptr[i] + k0, lA + i * 2048 + w * 512);
      load_lds16(bptr[i] + k0, lB + i * 2048 + w * 512);
    }
    __syncthreads();
#pragma unroll
    for (int kk = 0; kk < 2; ++kk) {
      short8 af[4], bfr[4];
#pragma unroll
      for (int mi = 0; mi < 4; ++mi)
        af[mi] = *(const short8*)(lA + (wm * 64 + mi * 16 + rrow) * BKT + kk * 32 + rq * 8);
#pragma unroll
      for (int ni = 0; ni < 4; ++ni)
        bfr[ni] = *(const short8*)(lB + (wn * 64 + ni * 16 + rrow) * BKT + kk * 32 + rq * 8);
#pragma unroll
      for (int mi = 0; mi < 4; ++mi)
#pragma unroll
        for (int ni = 0; ni < 4; ++ni)
          acc[mi][ni] = __builtin_amdgcn_mfma_f32_16x16x32_bf16(af[mi], bfr[ni], acc[mi][ni], 0, 0, 0);
    }
    __syncthreads();
  }
}

// ---------------------------------------------------------------------------
// fc1: hdn = relu(gather(xb) @ W1^T + b1); 128x128 tile, grid (32, 68).
// ---------------------------------------------------------------------------
__global__ __launch_bounds__(256, 2) void fc1_kernel(
    const unsigned short* __restrict__ xb, const unsigned short* __restrict__ wc1,
    const float* __restrict__ fc1_b, const int* __restrict__ offs,
    const int* __restrict__ counts, const int* __restrict__ slot_token,
    unsigned short* __restrict__ hdn, int chunk) {
  __shared__ unsigned short sA[BMT * BKT];
  __shared__ unsigned short sB[BNT * BKT];
  const int row0 = chunk * CHUNK_ROWS + blockIdx.y * BMT;
  if (row0 >= offs[E_NUM]) return;
  int e = 0;
#pragma unroll
  for (int i = 1; i < E_NUM; ++i) e = (row0 >= offs[i]) ? i : e;
  const int n0 = blockIdx.x * BNT;

  f32x4 acc[4][4];
  f32x4 zf = {0.f, 0.f, 0.f, 0.f};
#pragma unroll
  for (int mi = 0; mi < 4; ++mi)
#pragma unroll
    for (int ni = 0; ni < 4; ++ni) acc[mi][ni] = zf;

  const int tid = threadIdx.x;
  const int srow = tid >> 3;            // 8 lanes/row, 16B each over BK=64
  const int scol = (tid & 7) * 8;
  const unsigned short* Bm = wc1 + (size_t)e * DFF_DIM * H_DIM + (size_t)n0 * H_DIM;
  const unsigned short* aptr[4];
  const unsigned short* bptr[4];
#pragma unroll
  for (int i = 0; i < 4; ++i) {
    const int r = i * 32 + srow;
    const int tok = slot_token[row0 + r] & 0x7FFFFFFF;
    aptr[i] = xb + (size_t)tok * H_DIM + scol;
    bptr[i] = Bm + (size_t)r * H_DIM + scol;
  }
  gemm_core<H_DIM>(aptr, bptr, sA, sB, acc);

  const int w = tid >> 6;
  const int lane = tid & 63;
  const int wm = w >> 1, wn = w & 1;
  const int rrow = lane & 15, rq = lane >> 4;
  const int cnt = counts[e];
  const int lbase = row0 - offs[e];
  const int hrow0 = row0 - chunk * CHUNK_ROWS;
#pragma unroll
  for (int mi = 0; mi < 4; ++mi) {
#pragma unroll
    for (int j = 0; j < 4; ++j) {
      const int rit = wm * 64 + mi * 16 + rq * 4 + j;
      if (lbase + rit >= cnt) continue;
      unsigned short* hrow = hdn + (size_t)(hrow0 + rit) * DFF_DIM;
#pragma unroll
      for (int ni = 0; ni < 4; ++ni) {
        const int n = n0 + wn * 64 + ni * 16 + rrow;
        float v = acc[mi][ni][j] + fc1_b[e * DFF_DIM + n];
        v = v > 0.f ? v : 0.f;
        hrow[n] = f2bf(v);
      }
    }
  }
}

// ---------------------------------------------------------------------------
// fc2 v10: 256x128 tile, 8 waves (4M x 2N; per-wave 64x64 = the validated
// fragment math), BK=64, double-buffered 96KB LDS, T3-minimum 2-phase
// (STAGE next -> COMPUTE cur -> one __syncthreads). Regime-gate rationale:
// all pipelining was null at 128^2/4-wave (r10/r11, m232); m248v2 measured
// 2ph 256-class grouped K=1024 at 655-666 TF refcheck'd. Grid = 34m x 8n =
// 272 blocks (~1/CU; the pipeline, not churn, hides the stage latency).
// XCD slab swizzle (272 = 8 x 34, bijective). Epilogue: k=0 -> fp32 direct
// out, k=1 -> bf16 outk1; weights from ew[2*tok+k]. No atomics.
// ---------------------------------------------------------------------------
__global__ __launch_bounds__(512, 2) void fc2_kernel(
    const unsigned short* __restrict__ hdn, const unsigned short* __restrict__ wc2,
    const float* __restrict__ fc2_b, const int* __restrict__ offs,
    const int* __restrict__ counts, const int* __restrict__ slot_token,
    const float* __restrict__ ew, float* __restrict__ out,
    unsigned short* __restrict__ outk1, int chunk) {
  __shared__ unsigned short sA0[256 * 64];   // 32 KB
  __shared__ unsigned short sB0[128 * 64];   // 16 KB
  __shared__ unsigned short sA1[256 * 64];   // 32 KB
  __shared__ unsigned short sB1[128 * 64];   // 16 KB
  const int id = blockIdx.x;                 // 0..271
  const int xcd = id & 7, j = id >> 3;       // j 0..33
  const int g = xcd * MT2_PER_CHUNK + j;     // XCD slab, bijective
  const int ml = g >> 3;                     // 0..33
  const int nt = g & 7;                      // 0..7
  const int row0 = chunk * CHUNK_ROWS + ml * 256;
  if (row0 >= offs[E_NUM]) return;
  int e = 0;
#pragma unroll
  for (int i = 1; i < E_NUM; ++i) e = (row0 >= offs[i]) ? i : e;
  const int n0 = nt * 128;

  f32x4 acc[4][4];
  f32x4 zf = {0.f, 0.f, 0.f, 0.f};
#pragma unroll
  for (int mi = 0; mi < 4; ++mi)
#pragma unroll
    for (int ni = 0; ni < 4; ++ni) acc[mi][ni] = zf;

  const int tid = threadIdx.x;
  const int w = tid >> 6, lane = tid & 63;   // 8 waves
  const int wm = w >> 1, wn = w & 1;         // 4M x 2N
  const int rrow = lane & 15, rq = lane >> 4;
  const int srow = tid >> 3;                 // 0..63 (8 lanes/row)
  const int scol = (tid & 7) * 8;
  const unsigned short* A = hdn + (size_t)(ml * 256) * DFF_DIM;
  const unsigned short* Bm = wc2 + (size_t)e * H_DIM * DFF_DIM + (size_t)n0 * DFF_DIM;
  const unsigned short* aptr[4];
  const unsigned short* bptr[2];
#pragma unroll
  for (int i = 0; i < 4; ++i)
    aptr[i] = A + (size_t)(i * 64 + srow) * DFF_DIM + scol;
#pragma unroll
  for (int i = 0; i < 2; ++i)
    bptr[i] = Bm + (size_t)(i * 64 + srow) * DFF_DIM + scol;

  // LDS dest: wave-uniform base; pass i covers 64 rows, wave w stages 8 rows.
#define FC2_STAGE(DA, DB, K0)                                        \
  {                                                                  \
    _Pragma("unroll")                                                \
    for (int i = 0; i < 4; ++i)                                      \
      load_lds16(aptr[i] + (K0), (DA) + i * 4096 + w * 512);         \
    _Pragma("unroll")                                                \
    for (int i = 0; i < 2; ++i)                                      \
      load_lds16(bptr[i] + (K0), (DB) + i * 4096 + w * 512);         \
  }

#define FC2_COMPUTE(SA, SB)                                                         \
  {                                                                                 \
    _Pragma("unroll")                                                               \
    for (int kk = 0; kk < 2; ++kk) {                                                \
      short8 af[4], bfr[4];                                                         \
      _Pragma("unroll")                                                             \
      for (int mi = 0; mi < 4; ++mi)                                                \
        af[mi] = *(const short8*)((SA) + (wm * 64 + mi * 16 + rrow) * BKT + kk * 32 + rq * 8); \
      _Pragma("unroll")                                                             \
      for (int ni = 0; ni < 4; ++ni)                                                \
        bfr[ni] = *(const short8*)((SB) + (wn * 64 + ni * 16 + rrow) * BKT + kk * 32 + rq * 8); \
      _Pragma("unroll")                                                             \
      for (int mi = 0; mi < 4; ++mi)                                                \
        _Pragma("unroll")                                                           \
        for (int ni = 0; ni < 4; ++ni)                                              \
          acc[mi][ni] = __builtin_amdgcn_mfma_f32_16x16x32_bf16(af[mi], bfr[ni], acc[mi][ni], 0, 0, 0); \
    }                                                                               \
  }

  // Prologue: stage step 0.
  FC2_STAGE(sA0, sB0, 0)
  __syncthreads();
  // Steady state: 31 iters x 2 steps. Stage(t+1) issued BEFORE compute(t);
  // the single barrier (vmcnt0+lgkm0+s_barrier) lands after ~32 MFMA/wave of
  // cover, and guarantees buf safety for the overwrite two steps later.
  for (int ks = 0; ks < 62; ks += 2) {
    FC2_STAGE(sA1, sB1, (ks + 1) * BKT)
    FC2_COMPUTE(sA0, sB0)
    __syncthreads();
    FC2_STAGE(sA0, sB0, (ks + 2) * BKT)
    FC2_COMPUTE(sA1, sB1)
    __syncthreads();
  }
  FC2_STAGE(sA1, sB1, 63 * BKT)
  FC2_COMPUTE(sA0, sB0)      // step 62
  __syncthreads();           // drains stage(63)
  FC2_COMPUTE(sA1, sB1)      // step 63

#undef FC2_STAGE
#undef FC2_COMPUTE

  const int cnt = counts[e];
  const int lbase = row0 - offs[e];
#pragma unroll
  for (int mi = 0; mi < 4; ++mi) {
#pragma unroll
    for (int j2 = 0; j2 < 4; ++j2) {
      const int rit = wm * 64 + mi * 16 + rq * 4 + j2;   // 0..255
      if (lbase + rit >= cnt) continue;
      const int gr = row0 + rit;
      const int st = slot_token[gr];
      const int tok = st & 0x7FFFFFFF;
      const float wgt = ew[2 * tok + (st < 0 ? 1 : 0)];
#pragma unroll
      for (int ni = 0; ni < 4; ++ni) {
        const int h = n0 + wn * 64 + ni * 16 + rrow;
        const float v = (acc[mi][ni][j2] + fc2_b[e * H_DIM + h]) * wgt;
        if (st >= 0) out[(size_t)tok * H_DIM + h] = v;            // k=0, fp32
        else         outk1[(size_t)tok * H_DIM + h] = f2bf(v);    // k=1, bf16
      }
    }
  }
}

// ---------------------------------------------------------------------------
// Final add (atomic-free, deterministic): out[t] += bf2f(outk1[t]).
// ---------------------------------------------------------------------------
__global__ __launch_bounds__(256) void add_kernel(
    float* __restrict__ out, const unsigned short* __restrict__ outk1) {
  const int wave = threadIdx.x >> 6;
  const int lane = threadIdx.x & 63;
  const int t = blockIdx.x * 4 + wave;
  float4* orow = (float4*)(out + (size_t)t * H_DIM);
  const ushort4* krow = (const ushort4*)(outk1 + (size_t)t * H_DIM);
#pragma unroll
  for (int j = 0; j < 4; ++j) {
    const int idx = j * 64 + lane;
    float4 a = orow[idx];
    ushort4 b = krow[idx];
    a.x += bf2f(b.x); a.y += bf2f(b.y); a.z += bf2f(b.z); a.w += bf2f(b.w);
    orow[idx] = a;
  }
}

// ---------------------------------------------------------------------------
extern "C" void kernel_launch(void* const* d_in, const int* in_sizes, int n_in,
                              void* d_out, int out_size, void* d_ws, size_t ws_size,
                              hipStream_t stream) {
  const float* x        = (const float*)d_in[0];
  const float* router_w = (const float*)d_in[1];
  const float* router_b = (const float*)d_in[2];
  const float* fc1_w    = (const float*)d_in[3];
  const float* fc1_b    = (const float*)d_in[4];
  const float* fc2_w    = (const float*)d_in[5];
  const float* fc2_b    = (const float*)d_in[6];
  float* out = (float*)d_out;

  char* ws = (char*)d_ws;
  int* counts            = (int*)(ws + WS_COUNTS);
  int* cursor            = (int*)(ws + WS_CURSOR);
  int* offs              = (int*)(ws + WS_OFFS);
  int* slot_token        = (int*)(ws + WS_SLOT_TOK);
  int* eidx              = (int*)(ws + WS_EIDX);
  float* ew              = (float*)(ws + WS_EW);
  unsigned short* wc1    = (unsigned short*)(ws + WS_WC1);
  unsigned short* wc2    = (unsigned short*)(ws + WS_WC2);
  unsigned short* xb     = (unsigned short*)(ws + WS_XB);
  unsigned short* hdn    = (unsigned short*)(ws + WS_HDN);
  unsigned short* outk1  = (unsigned short*)(ws + WS_OUTK1);

  if (ws_size < WS_REQUIRED) {
    hipMemsetAsync(d_out, 0, (size_t)T_TOKENS * H_DIM * sizeof(float), stream);
    return;  // output stays zero -> diagnosable failure
  }
  hipMemsetAsync(ws, 0, WS_SMALL_ZERO, stream);  // counts/cursor/offs/slot_token

  convert_weights<<<CONV_BLOCKS, 256, 0, stream>>>(fc1_w, fc2_w, wc1, wc2);
  router_kernel<<<T_TOKENS / 16, 256, 0, stream>>>(x, router_w, router_b, xb, eidx, ew);
  count_kernel<<<1, 1024, 0, stream>>>(eidx, counts, offs, cursor);
  scatter_kernel<<<T_TOKENS / 1024, 1024, 0, stream>>>(eidx, offs, cursor, slot_token);

  for (int c = 0; c < NCHUNK; ++c) {
    fc1_kernel<<<dim3(DFF_DIM / BNT, MT1_PER_CHUNK), 256, 0, stream>>>(
        xb, wc1, fc1_b, offs, counts, slot_token, hdn, c);
    fc2_kernel<<<8 * MT2_PER_CHUNK, 512, 0, stream>>>(
        hdn, wc2, fc2_b, offs, counts, slot_token, ew, out, outk1, c);
  }
  add_kernel<<<T_TOKENS / 4, 256, 0, stream>>>(out, outk1);
}

// Round 17
// 1048.885 us; speedup vs baseline: 1.4098x; 1.4098x over previous
//
#include <hip/hip_runtime.h>
#include <stdint.h>

// Problem constants
#define T_TOKENS 16384
#define H_DIM 1024
#define E_NUM 8
#define DFF_DIM 4096

// GEMM tiling
#define BMT 128
#define BNT 128
#define BKT 64
#define MT_CAP 264                       // max padded m-tiles
#define PAD_ROWS (MT_CAP * BMT)          // 33792
#define NCHUNK 4
#define MT_PER_CHUNK (MT_CAP / NCHUNK)   // 66
#define CHUNK_ROWS (MT_PER_CHUNK * BMT)  // 8448

// Workspace layout (bytes) — identical to round 7 (fully validated config)
#define WS_COUNTS     0
#define WS_CURSOR     32
#define WS_OFFS       64
#define WS_SLOT_TOK   256
#define WS_SLOT_W     135424
#define WS_EIDX       270592
#define WS_EW         401664
#define WS_WC1        532736
#define WS_WC2        67641600
#define WS_XB         134750464
#define WS_HDN        168304896          // CHUNK_ROWS x DFF bf16 = 69,206,016
#define WS_OUTK1      237510912          // T x H bf16 = 33,554,432
#define WS_REQUIRED   271065344UL        // <= 273,162,496 proven available
#define WS_SMALL_ZERO 270592

typedef __attribute__((ext_vector_type(8))) short short8;
typedef __attribute__((ext_vector_type(4))) float f32x4;

__device__ __forceinline__ unsigned short f2bf(float f) {
  union { float f; unsigned int u; } v; v.f = f;
  unsigned int r = v.u + 0x7FFFu + ((v.u >> 16) & 1u);  // round-nearest-even
  return (unsigned short)(r >> 16);
}

__device__ __forceinline__ float bf2f(unsigned short b) {
  union { unsigned int u; float f; } v; v.u = ((unsigned int)b) << 16;
  return v.f;
}

__device__ __forceinline__ void load_lds16(const void* g, void* l) {
  __builtin_amdgcn_global_load_lds(
      (const __attribute__((address_space(1))) void*)g,
      (__attribute__((address_space(3))) void*)l, 16, 0, 0);
}

// ---------------------------------------------------------------------------
// Weight fp32 -> bf16 conversion. Grid-stride (round-13 profile: 32768
// one-shot micro-blocks ran at 2.6 TB/s, per-block launch/drain bound).
// LINEAR layout — validated round 15.
// ---------------------------------------------------------------------------
#define CONV_BLOCKS 2048
__global__ __launch_bounds__(256) void convert_weights(
    const float* __restrict__ w1, const float* __restrict__ w2,
    unsigned short* __restrict__ wc1, unsigned short* __restrict__ wc2) {
  const int total4 = (E_NUM * DFF_DIM * H_DIM) / 4;  // 8388608
  const int step = CONV_BLOCKS * 256;
  for (int i = blockIdx.x * 256 + threadIdx.x; i < total4; i += step) {
    float4 a = ((const float4*)w1)[i];
    float4 b = ((const float4*)w2)[i];
    ushort4 ua, ub;
    ua.x = f2bf(a.x); ua.y = f2bf(a.y); ua.z = f2bf(a.z); ua.w = f2bf(a.w);
    ub.x = f2bf(b.x); ub.y = f2bf(b.y); ub.z = f2bf(b.z); ub.w = f2bf(b.w);
    ((ushort4*)wc1)[i] = ua;
    ((ushort4*)wc2)[i] = ub;
  }
}

// ---------------------------------------------------------------------------
// Router: no global atomics (round-2 lesson). Emits x as bf16 (xb).
// ---------------------------------------------------------------------------
__global__ __launch_bounds__(256) void router_kernel(
    const float* __restrict__ x, const float* __restrict__ rw,
    const float* __restrict__ rb, unsigned short* __restrict__ xb,
    int* __restrict__ eidx, float* __restrict__ ew) {
  __shared__ float4 rws[E_NUM * 256];
  const int tid = threadIdx.x;
#pragma unroll
  for (int k = 0; k < 8; ++k) rws[k * 256 + tid] = ((const float4*)rw)[k * 256 + tid];
  __syncthreads();

  const int wave = tid >> 6;
  const int lane = tid & 63;
#pragma unroll
  for (int i = 0; i < 4; ++i) {
    const int t = blockIdx.x * 16 + wave * 4 + i;
    const float4* xrow = (const float4*)(x + (size_t)t * H_DIM);
    float4 xv[4];
#pragma unroll
    for (int j = 0; j < 4; ++j) xv[j] = xrow[j * 64 + lane];

    ushort4* xbrow = (ushort4*)(xb + (size_t)t * H_DIM);
#pragma unroll
    for (int j = 0; j < 4; ++j) {
      ushort4 o;
      o.x = f2bf(xv[j].x); o.y = f2bf(xv[j].y);
      o.z = f2bf(xv[j].z); o.w = f2bf(xv[j].w);
      xbrow[j * 64 + lane] = o;
    }

    float s[E_NUM];
#pragma unroll
    for (int e = 0; e < E_NUM; ++e) {
      float a = 0.f;
#pragma unroll
      for (int j = 0; j < 4; ++j) {
        float4 wv = rws[e * 256 + j * 64 + lane];
        a += xv[j].x * wv.x + xv[j].y * wv.y + xv[j].z * wv.z + xv[j].w * wv.w;
      }
      s[e] = a;
    }
#pragma unroll
    for (int off = 32; off; off >>= 1) {
#pragma unroll
      for (int e = 0; e < E_NUM; ++e) s[e] += __shfl_xor(s[e], off);
    }
    if (lane == 0) {
      float lg[E_NUM];
#pragma unroll
      for (int e = 0; e < E_NUM; ++e) lg[e] = s[e] + rb[e];
      int i0 = 0; float m0 = lg[0];
#pragma unroll
      for (int e = 1; e < E_NUM; ++e)
        if (lg[e] > m0) { m0 = lg[e]; i0 = e; }
      int i1 = -1; float m1 = -3.4e38f;
#pragma unroll
      for (int e = 0; e < E_NUM; ++e)
        if (e != i0 && lg[e] > m1) { m1 = lg[e]; i1 = e; }
      float e1 = expf(m1 - m0);
      float denom = 1.f + e1;
      ((int2*)eidx)[t] = make_int2(i0, i1);
      ((float2*)ew)[t] = make_float2(1.f / denom, e1 / denom);
    }
  }
}

// ---------------------------------------------------------------------------
// count_kernel: single block, register histogram, LDS atomics only.
// ---------------------------------------------------------------------------
__global__ __launch_bounds__(1024) void count_kernel(const int* __restrict__ eidx,
                                                     int* __restrict__ counts,
                                                     int* __restrict__ offs,
                                                     int* __restrict__ cursor) {
  __shared__ int hist[E_NUM];
  const int tid = threadIdx.x;
  const int lane = tid & 63;
  if (tid < E_NUM) hist[tid] = 0;
  __syncthreads();
  int c[E_NUM];
#pragma unroll
  for (int e = 0; e < E_NUM; ++e) c[e] = 0;
  const int4* p = (const int4*)eidx;
#pragma unroll
  for (int i = 0; i < 8; ++i) {
    int4 v = p[i * 1024 + tid];
#pragma unroll
    for (int e = 0; e < E_NUM; ++e)
      c[e] += (v.x == e) + (v.y == e) + (v.z == e) + (v.w == e);
  }
#pragma unroll
  for (int off = 32; off; off >>= 1) {
#pragma unroll
    for (int e = 0; e < E_NUM; ++e) c[e] += __shfl_xor(c[e], off);
  }
  if (lane == 0) {
#pragma unroll
    for (int e = 0; e < E_NUM; ++e) atomicAdd(&hist[e], c[e]);
  }
  __syncthreads();
  if (tid == 0) {
    int acc = 0;
    offs[0] = 0;
#pragma unroll
    for (int e = 0; e < E_NUM; ++e) {
      counts[e] = hist[e];
      cursor[e] = 0;
      acc += ((hist[e] + BMT - 1) / BMT) * BMT;
      offs[e + 1] = acc;
    }
  }
}

// ---------------------------------------------------------------------------
// Scatter: ballot-rank compaction (128 global atomics total). slot_token
// carries the k-flag in bit 31 (k=0 -> fp32 direct-out, k=1 -> outk1).
// ---------------------------------------------------------------------------
__global__ __launch_bounds__(1024) void scatter_kernel(
    const int* __restrict__ eidx, const float* __restrict__ ew,
    const int* __restrict__ offs, int* __restrict__ cursor,
    int* __restrict__ slot_token, float* __restrict__ slot_w) {
  __shared__ int wcnt[16][E_NUM];
  __shared__ int wpre[16][E_NUM];
  __shared__ int bbase[E_NUM];
  __shared__ int soffs[E_NUM];
  const int tid = threadIdx.x, w = tid >> 6, lane = tid & 63;
  const int t = blockIdx.x * 1024 + tid;
  const int2 epair = ((const int2*)eidx)[t];
  const float2 wpair = ((const float2*)ew)[t];
  const int e0 = epair.x, e1 = epair.y;
  const unsigned long long lt = (1ULL << lane) - 1ULL;
  if (tid < E_NUM) soffs[tid] = offs[tid];
  int r0 = 0, r1 = 0;
#pragma unroll
  for (int e = 0; e < E_NUM; ++e) {
    unsigned long long m0 = __ballot(e0 == e);
    unsigned long long m1 = __ballot(e1 == e);
    int c0 = __popcll(m0);
    if (e0 == e) r0 = __popcll(m0 & lt);
    if (e1 == e) r1 = c0 + __popcll(m1 & lt);
    if (lane == 0) wcnt[w][e] = c0 + __popcll(m1);
  }
  __syncthreads();
  if (tid < E_NUM) {
    int run = 0;
#pragma unroll
    for (int w2 = 0; w2 < 16; ++w2) {
      wpre[w2][tid] = run;
      run += wcnt[w2][tid];
    }
    bbase[tid] = atomicAdd(&cursor[tid], run);
  }
  __syncthreads();
  const int s0 = soffs[e0] + bbase[e0] + wpre[w][e0] + r0;
  const int s1 = soffs[e1] + bbase[e1] + wpre[w][e1] + r1;
  slot_token[s0] = t;                       // k=0
  slot_w[s0] = wpair.x;
  slot_token[s1] = t | (int)0x80000000;     // k=1
  slot_w[s1] = wpair.y;
}

// ---------------------------------------------------------------------------
// GEMM core (BK=64, round-5 proven): C[128x128] = A[128xK] * B[128xK]^T.
// Per-lane staging source pointers allow gathered A rows. 4 waves, each owns
// a 64x64 C quadrant.
// ---------------------------------------------------------------------------
template <int KTOT>
__device__ __forceinline__ void gemm_core(const unsigned short* const* aptr,
                                          const unsigned short* const* bptr,
                                          unsigned short* lA, unsigned short* lB,
                                          f32x4 acc[4][4]) {
  const int tid = threadIdx.x;
  const int w = tid >> 6, lane = tid & 63;
  const int wm = w >> 1, wn = w & 1;
  const int rrow = lane & 15;
  const int rq = lane >> 4;

  for (int ks = 0; ks < KTOT / BKT; ++ks) {
    const int k0 = ks * BKT;
#pragma unroll
    for (int i = 0; i < 4; ++i) {
      load_lds16(aptr[i] + k0, lA + i * 2048 + w * 512);
      load_lds16(bptr[i] + k0, lB + i * 2048 + w * 512);
    }
    __syncthreads();
#pragma unroll
    for (int kk = 0; kk < 2; ++kk) {
      short8 af[4], bfr[4];
#pragma unroll
      for (int mi = 0; mi < 4; ++mi)
        af[mi] = *(const short8*)(lA + (wm * 64 + mi * 16 + rrow) * BKT + kk * 32 + rq * 8);
#pragma unroll
      for (int ni = 0; ni < 4; ++ni)
        bfr[ni] = *(const short8*)(lB + (wn * 64 + ni * 16 + rrow) * BKT + kk * 32 + rq * 8);
#pragma unroll
      for (int mi = 0; mi < 4; ++mi)
#pragma unroll
        for (int ni = 0; ni < 4; ++ni)
          acc[mi][ni] = __builtin_amdgcn_mfma_f32_16x16x32_bf16(af[mi], bfr[ni], acc[mi][ni], 0, 0, 0);
    }
    __syncthreads();
  }
}

// ---------------------------------------------------------------------------
// fc1: hdn = relu(gather(xb) @ W1^T + b1); BK=64 (m97-ceiling structure,
// measured 886 TF). A gathered via slot_token in the gload_lds source addrs.
// ---------------------------------------------------------------------------
__global__ __launch_bounds__(256, 2) void fc1_kernel(
    const unsigned short* __restrict__ xb, const unsigned short* __restrict__ wc1,
    const float* __restrict__ fc1_b, const int* __restrict__ offs,
    const int* __restrict__ counts, const int* __restrict__ slot_token,
    unsigned short* __restrict__ hdn, int chunk) {
  __shared__ unsigned short sA[BMT * BKT];
  __shared__ unsigned short sB[BNT * BKT];
  const int mt = chunk * MT_PER_CHUNK + blockIdx.y;
  const int row0 = mt * BMT;
  if (row0 >= offs[E_NUM]) return;
  int e = 0;
#pragma unroll
  for (int i = 1; i < E_NUM; ++i) e = (row0 >= offs[i]) ? i : e;
  const int n0 = blockIdx.x * BNT;

  f32x4 acc[4][4];
  f32x4 zf = {0.f, 0.f, 0.f, 0.f};
#pragma unroll
  for (int mi = 0; mi < 4; ++mi)
#pragma unroll
    for (int ni = 0; ni < 4; ++ni) acc[mi][ni] = zf;

  const int tid = threadIdx.x;
  const int srow = tid >> 3;            // 8 lanes/row, 16B each over BK=64
  const int scol = (tid & 7) * 8;
  const unsigned short* Bm = wc1 + (size_t)e * DFF_DIM * H_DIM + (size_t)n0 * H_DIM;
  const unsigned short* aptr[4];
  const unsigned short* bptr[4];
#pragma unroll
  for (int i = 0; i < 4; ++i) {
    const int r = i * 32 + srow;
    const int tok = slot_token[row0 + r] & 0x7FFFFFFF;
    aptr[i] = xb + (size_t)tok * H_DIM + scol;
    bptr[i] = Bm + (size_t)r * H_DIM + scol;
  }
  gemm_core<H_DIM>(aptr, bptr, sA, sB, acc);

  const int w = tid >> 6;
  const int lane = tid & 63;
  const int wm = w >> 1, wn = w & 1;
  const int rrow = lane & 15, rq = lane >> 4;
  const int cnt = counts[e];
  const int lbase = row0 - offs[e];
  const int hrow0 = row0 - chunk * CHUNK_ROWS;
#pragma unroll
  for (int mi = 0; mi < 4; ++mi) {
#pragma unroll
    for (int j = 0; j < 4; ++j) {
      const int rit = wm * 64 + mi * 16 + rq * 4 + j;
      if (lbase + rit >= cnt) continue;
      unsigned short* hrow = hdn + (size_t)(hrow0 + rit) * DFF_DIM;
#pragma unroll
      for (int ni = 0; ni < 4; ++ni) {
        const int n = n0 + wn * 64 + ni * 16 + rrow;
        float v = acc[mi][ni][j] + fc1_b[e * DFF_DIM + n];
        v = v > 0.f ? v : 0.f;
        hrow[n] = f2bf(v);
      }
    }
  }
}

// ---------------------------------------------------------------------------
// fc2: BK=64, 128x128 tile, 2D-chunked XCD swizzle (validated r7 structure:
// FETCH 85MB). Epilogue: k=0 rows -> w*(acc+b) fp32 direct to out (each
// token exactly once, race-free); k=1 rows -> bf16 outk1. No atomics.
// Structural note (rounds 4-16): this 2-barrier K-loop at <=4 blocks/CU is
// step-latency-locked at ~460 TF; atomics/fetch/occupancy/pipelining/tile
// variants all counter-eliminated or regressed. The escape is the full
// 8-phase counted-vmcnt schedule (m201), out of one-shot-port budget here.
// ---------------------------------------------------------------------------
__global__ __launch_bounds__(256, 2) void fc2_kernel(
    const unsigned short* __restrict__ hdn, const unsigned short* __restrict__ wc2,
    const float* __restrict__ fc2_b, const int* __restrict__ offs,
    const int* __restrict__ counts, const int* __restrict__ slot_token,
    const float* __restrict__ slot_w, float* __restrict__ out,
    unsigned short* __restrict__ outk1, int chunk) {
  __shared__ unsigned short sA[BMT * BKT];
  __shared__ unsigned short sB[BNT * BKT];
  // Bijective 2D-chunked XCD swizzle over (66 m) x (8 n) = 528 blocks.
  const int id = blockIdx.x;
  const int xcd = id & 7, j = id >> 3;
  int ml, nt;
  if (j < 64) { ml = xcd * 8 + (j & 7); nt = j >> 3; }
  else        { ml = 64 + (j & 1);      nt = xcd;    }
  const int mt = chunk * MT_PER_CHUNK + ml;
  const int row0 = mt * BMT;
  if (row0 >= offs[E_NUM]) return;
  int e = 0;
#pragma unroll
  for (int i = 1; i < E_NUM; ++i) e = (row0 >= offs[i]) ? i : e;
  const int n0 = nt * BNT;

  f32x4 acc[4][4];
  f32x4 zf = {0.f, 0.f, 0.f, 0.f};
#pragma unroll
  for (int mi = 0; mi < 4; ++mi)
#pragma unroll
    for (int ni = 0; ni < 4; ++ni) acc[mi][ni] = zf;

  const int tid = threadIdx.x;
  const int srow = tid >> 3;
  const int scol = (tid & 7) * 8;
  const unsigned short* A = hdn + (size_t)(ml * BMT) * DFF_DIM;
  const unsigned short* Bm = wc2 + (size_t)e * H_DIM * DFF_DIM + (size_t)n0 * DFF_DIM;
  const unsigned short* aptr[4];
  const unsigned short* bptr[4];
#pragma unroll
  for (int i = 0; i < 4; ++i) {
    const int r = i * 32 + srow;
    aptr[i] = A + (size_t)r * DFF_DIM + scol;
    bptr[i] = Bm + (size_t)r * DFF_DIM + scol;
  }
  gemm_core<DFF_DIM>(aptr, bptr, sA, sB, acc);

  const int w = tid >> 6;
  const int lane = tid & 63;
  const int wm = w >> 1, wn = w & 1;
  const int rrow = lane & 15, rq = lane >> 4;
  const int cnt = counts[e];
  const int lbase = row0 - offs[e];
#pragma unroll
  for (int mi = 0; mi < 4; ++mi) {
#pragma unroll
    for (int j2 = 0; j2 < 4; ++j2) {
      const int rit = wm * 64 + mi * 16 + rq * 4 + j2;
      if (lbase + rit >= cnt) continue;
      const int gr = row0 + rit;
      const int st = slot_token[gr];
      const int tok = st & 0x7FFFFFFF;
      const float wgt = slot_w[gr];
#pragma unroll
      for (int ni = 0; ni < 4; ++ni) {
        const int h = n0 + wn * 64 + ni * 16 + rrow;
        const float v = (acc[mi][ni][j2] + fc2_b[e * H_DIM + h]) * wgt;
        if (st >= 0) out[(size_t)tok * H_DIM + h] = v;            // k=0, fp32
        else         outk1[(size_t)tok * H_DIM + h] = f2bf(v);    // k=1, bf16
      }
    }
  }
}

// ---------------------------------------------------------------------------
// Final add (atomic-free, deterministic): out[t] += bf2f(outk1[t]).
// ---------------------------------------------------------------------------
__global__ __launch_bounds__(256) void add_kernel(
    float* __restrict__ out, const unsigned short* __restrict__ outk1) {
  const int wave = threadIdx.x >> 6;
  const int lane = threadIdx.x & 63;
  const int t = blockIdx.x * 4 + wave;
  float4* orow = (float4*)(out + (size_t)t * H_DIM);
  const ushort4* krow = (const ushort4*)(outk1 + (size_t)t * H_DIM);
#pragma unroll
  for (int j = 0; j < 4; ++j) {
    const int idx = j * 64 + lane;
    float4 a = orow[idx];
    ushort4 b = krow[idx];
    a.x += bf2f(b.x); a.y += bf2f(b.y); a.z += bf2f(b.z); a.w += bf2f(b.w);
    orow[idx] = a;
  }
}

// ---------------------------------------------------------------------------
extern "C" void kernel_launch(void* const* d_in, const int* in_sizes, int n_in,
                              void* d_out, int out_size, void* d_ws, size_t ws_size,
                              hipStream_t stream) {
  const float* x        = (const float*)d_in[0];
  const float* router_w = (const float*)d_in[1];
  const float* router_b = (const float*)d_in[2];
  const float* fc1_w    = (const float*)d_in[3];
  const float* fc1_b    = (const float*)d_in[4];
  const float* fc2_w    = (const float*)d_in[5];
  const float* fc2_b    = (const float*)d_in[6];
  float* out = (float*)d_out;

  char* ws = (char*)d_ws;
  int* counts            = (int*)(ws + WS_COUNTS);
  int* cursor            = (int*)(ws + WS_CURSOR);
  int* offs              = (int*)(ws + WS_OFFS);
  int* slot_token        = (int*)(ws + WS_SLOT_TOK);
  float* slot_w          = (float*)(ws + WS_SLOT_W);
  int* eidx              = (int*)(ws + WS_EIDX);
  float* ew              = (float*)(ws + WS_EW);
  unsigned short* wc1    = (unsigned short*)(ws + WS_WC1);
  unsigned short* wc2    = (unsigned short*)(ws + WS_WC2);
  unsigned short* xb     = (unsigned short*)(ws + WS_XB);
  unsigned short* hdn    = (unsigned short*)(ws + WS_HDN);
  unsigned short* outk1  = (unsigned short*)(ws + WS_OUTK1);

  if (ws_size < WS_REQUIRED) {
    hipMemsetAsync(d_out, 0, (size_t)T_TOKENS * H_DIM * sizeof(float), stream);
    return;  // output stays zero -> diagnosable failure
  }
  hipMemsetAsync(ws, 0, WS_SMALL_ZERO, stream);  // zero counts/cursor/offs/slots

  convert_weights<<<CONV_BLOCKS, 256, 0, stream>>>(fc1_w, fc2_w, wc1, wc2);
  router_kernel<<<T_TOKENS / 16, 256, 0, stream>>>(x, router_w, router_b, xb, eidx, ew);
  count_kernel<<<1, 1024, 0, stream>>>(eidx, counts, offs, cursor);
  scatter_kernel<<<T_TOKENS / 1024, 1024, 0, stream>>>(eidx, ew, offs, cursor, slot_token, slot_w);

  for (int c = 0; c < NCHUNK; ++c) {
    fc1_kernel<<<dim3(DFF_DIM / BNT, MT_PER_CHUNK), 256, 0, stream>>>(
        xb, wc1, fc1_b, offs, counts, slot_token, hdn, c);
    fc2_kernel<<<8 * MT_PER_CHUNK, 256, 0, stream>>>(
        hdn, wc2, fc2_b, offs, counts, slot_token, slot_w, out, outk1, c);
  }
  add_kernel<<<T_TOKENS / 4, 256, 0, stream>>>(out, outk1);
}